// Round 3
// baseline (522.408 us; speedup 1.0000x reference)
//
#include <hip/hip_runtime.h>

#define N_NODES 8192
#define DIM 128

typedef short bf16x8 __attribute__((ext_vector_type(8)));
typedef float f32x4 __attribute__((ext_vector_type(4)));

__device__ __forceinline__ unsigned short f2bf_rne(float x) {
    unsigned int u = __builtin_bit_cast(unsigned int, x);
    u += 0x7fffu + ((u >> 16) & 1u);   // round-to-nearest-even
    return (unsigned short)(u >> 16);
}
__device__ __forceinline__ float bf2f(unsigned short h) {
    unsigned int u = ((unsigned int)h) << 16;
    return __builtin_bit_cast(float, u);
}

// ---------------- K1: d = rsqrt(rowsum(A) + 1) --------------------------
__global__ __launch_bounds__(256) void k_rowsum(const float* __restrict__ A,
                                                float* __restrict__ d) {
    int row = blockIdx.x;
    const float4* Ar = (const float4*)(A + (size_t)row * N_NODES);
    int t = threadIdx.x;
    float s = 0.f;
#pragma unroll
    for (int i = 0; i < 8; ++i) {
        float4 v = Ar[t + i * 256];
        s += (v.x + v.y) + (v.z + v.w);
    }
#pragma unroll
    for (int off = 32; off > 0; off >>= 1)
        s += __shfl_down(s, off, 64);
    __shared__ float wsum[4];
    if ((t & 63) == 0) wsum[t >> 6] = s;
    __syncthreads();
    if (t == 0) {
        float tot = wsum[0] + wsum[1] + wsum[2] + wsum[3] + 1.0f;  // +I diag
        d[row] = rsqrtf(tot);
    }
}

// ---------------- K2: Zt = bf16( diag(d) * X * W^T ) transposed ---------
// Zt[col][row], col=0..127 (output feature), row=0..8191 (node)
__global__ __launch_bounds__(256) void k_zgemm(const float* __restrict__ X,
                                               const float* __restrict__ W,
                                               const float* __restrict__ d,
                                               unsigned short* __restrict__ Zt) {
    __shared__ float Xs[64][129];
    __shared__ float Ws[64][129];
    int rb = blockIdx.x >> 1;
    int cb = blockIdx.x & 1;
    int t = threadIdx.x;
    const float4* Xg = (const float4*)(X + (size_t)rb * 64 * DIM);
    const float4* Wg = (const float4*)(W + (size_t)cb * 64 * DIM);
#pragma unroll
    for (int i = 0; i < 8; ++i) {
        int f = t + i * 256;
        int r = f >> 5;
        int c = (f & 31) << 2;
        float4 v = Xg[f];
        Xs[r][c] = v.x; Xs[r][c + 1] = v.y; Xs[r][c + 2] = v.z; Xs[r][c + 3] = v.w;
        float4 w = Wg[f];
        Ws[r][c] = w.x; Ws[r][c + 1] = w.y; Ws[r][c + 2] = w.z; Ws[r][c + 3] = w.w;
    }
    __syncthreads();
    int tx = t & 15, ty = t >> 4;
    float acc[4][4] = {};
    for (int k = 0; k < DIM; ++k) {
        float xr[4], wr[4];
#pragma unroll
        for (int i = 0; i < 4; ++i) xr[i] = Xs[ty * 4 + i][k];
#pragma unroll
        for (int j = 0; j < 4; ++j) wr[j] = Ws[tx * 4 + j][k];
#pragma unroll
        for (int i = 0; i < 4; ++i)
#pragma unroll
            for (int j = 0; j < 4; ++j)
                acc[i][j] += xr[i] * wr[j];
    }
#pragma unroll
    for (int i = 0; i < 4; ++i) {
        int row = rb * 64 + ty * 4 + i;
        float dv = d[row];
#pragma unroll
        for (int j = 0; j < 4; ++j) {
            int col = cb * 64 + tx * 4 + j;
            Zt[(size_t)col * N_NODES + row] = f2bf_rne(dv * acc[i][j]);
        }
    }
}

// ---------------- K3: out = diag(d) * ((A+I) @ Z) + b -------------------
// Simplest possible MFMA SpMM: one wave per block, 16 rows x all 128 cols,
// full K per wave. No LDS, no barriers, no split-K.
__global__ __launch_bounds__(64) void k_spmm(const float* __restrict__ A,
                                             const unsigned short* __restrict__ Zt,
                                             const float* __restrict__ d,
                                             const float* __restrict__ bias,
                                             float* __restrict__ out) {
    int lane = threadIdx.x;
    int l15 = lane & 15, quad = lane >> 4;
    int row0 = blockIdx.x * 16;

    // A-fragment base: lane holds A[row0+l15][k + quad*8 + j], j=0..7
    const float* Arow = A + (size_t)(row0 + l15) * N_NODES + quad * 8;
    // B-fragment base: lane holds Z[k + quad*8 + j][n*16 + l15]
    const unsigned short* Zb = Zt + (size_t)l15 * N_NODES + quad * 8;

    f32x4 acc[8];
#pragma unroll
    for (int i = 0; i < 8; ++i) acc[i] = (f32x4){0.f, 0.f, 0.f, 0.f};

    for (int k = 0; k < N_NODES; k += 32) {
        f32x4 a0 = *(const f32x4*)(Arow + k);
        f32x4 a1 = *((const f32x4*)(Arow + k) + 1);
        bf16x8 af;
        af[0] = (short)f2bf_rne(a0[0]); af[1] = (short)f2bf_rne(a0[1]);
        af[2] = (short)f2bf_rne(a0[2]); af[3] = (short)f2bf_rne(a0[3]);
        af[4] = (short)f2bf_rne(a1[0]); af[5] = (short)f2bf_rne(a1[1]);
        af[6] = (short)f2bf_rne(a1[2]); af[7] = (short)f2bf_rne(a1[3]);
        bf16x8 bfr[8];
#pragma unroll
        for (int n = 0; n < 8; ++n)
            bfr[n] = *(const bf16x8*)(Zb + (size_t)n * 16 * N_NODES + k);
#pragma unroll
        for (int n = 0; n < 8; ++n)
            acc[n] = __builtin_amdgcn_mfma_f32_16x16x32_bf16(af, bfr[n], acc[n], 0, 0, 0);
    }

    // epilogue: + identity term (Z row), row scale d, bias
#pragma unroll
    for (int n = 0; n < 8; ++n) {
        int col = n * 16 + l15;
        float bcol = bias[col];
#pragma unroll
        for (int r = 0; r < 4; ++r) {
            int row = row0 + quad * 4 + r;
            float zid = bf2f(Zt[(size_t)col * N_NODES + row]);
            out[(size_t)row * DIM + col] = d[row] * (acc[n][r] + zid) + bcol;
        }
    }
}

extern "C" void kernel_launch(void* const* d_in, const int* in_sizes, int n_in,
                              void* d_out, int out_size, void* d_ws, size_t ws_size,
                              hipStream_t stream) {
    const float* X = (const float*)d_in[0];
    const float* A = (const float*)d_in[1];
    const float* W = (const float*)d_in[2];
    const float* b = (const float*)d_in[3];
    float* out = (float*)d_out;

    char* ws = (char*)d_ws;
    float* dinv = (float*)ws;                              // 32 KB
    unsigned short* Zt = (unsigned short*)(ws + 32768);    // 2 MB bf16 [128][8192]
    // total workspace use: 2.03 MB (was 6.03 MB — possible ws_size overrun)

    k_rowsum<<<N_NODES, 256, 0, stream>>>(A, dinv);
    k_zgemm<<<256, 256, 0, stream>>>(X, W, dinv, Zt);
    k_spmm<<<512, 64, 0, stream>>>(A, Zt, dinv, b, out);
}